// Round 16
// baseline (106.797 us; speedup 1.0000x reference)
//
#include <hip/hip_runtime.h>

// 5-level wavedec (filter len 8, pywt 'symmetric'), 4096 rows of 8192 f32.
// Lengths: 8192 -> 4099 -> 2053 -> 1030 -> 518 -> 262
// Out: approx(262) @0, d5(262), d4(518), d3(1030), d2(2053), d1(4099).
//
// R16: minimum-LDS residency play. Only a1 lives in LDS (16.4 KB ->
// 8 blocks/CU = 32 waves = 100% theoretical occupancy, vs 44% at R10).
// a2 round-trips through global scratch (written coalesced by L2, re-read
// by L3 on the same CU -> same-XCD L2 hit, ~8 KB/row); a3 reuses bufA
// [0..1029] (a1 dead), a4 reuses bufA[2048..2565]. Inner loops identical
// to R10 (best, 58.4us). Falls back to R10 full-LDS form if ws too small.

static constexpr int ROWS = 4096;
static constexpr int N0 = 8192;
static constexpr int L1n = 4099, L2n = 2053, L3n = 1030, L4n = 518, L5n = 262;
static constexpr size_t OFF_D5 = 1073152u;
static constexpr size_t OFF_D4 = 2146304u;
static constexpr size_t OFF_D3 = 4268032u;
static constexpr size_t OFF_D2 = 8486912u;
static constexpr size_t OFF_D1 = 16896000u;

static constexpr int WS_STRIDE = 2056;   // floats per row slice (16B-aligned)
static constexpr size_t WS_NEED = (size_t)ROWS * WS_STRIDE * sizeof(float);

// Barrier ordering LDS only (no vmcnt drain).
__device__ __forceinline__ void barrier_lds() {
    asm volatile("s_waitcnt lgkmcnt(0)\n\ts_barrier" ::: "memory");
}

__device__ __forceinline__ float refl_load(const float* __restrict__ s, int idx, int n) {
    int i = (idx < 0) ? (-1 - idx) : ((idx >= n) ? (2 * n - 1 - idx) : idx);
    return s[i];
}

// Clamped 16-float window load for group j: w[t] = src[8j-6+t]
template <int N>
__device__ __forceinline__ void load_window(const float* __restrict__ src,
                                            int j, float* __restrict__ w) {
    constexpr int jmax = (N - 10) >> 3;
    const int jb = j < 1 ? 1 : (j > jmax ? jmax : j);
    const float2* __restrict__ s2 = reinterpret_cast<const float2*>(src) + (4 * jb - 3);
#pragma unroll
    for (int t = 0; t < 8; ++t) {
        const float2 v = s2[t];
        w[2 * t] = v.x; w[2 * t + 1] = v.y;
    }
}

// Branchy symmetric-reflect path for edge / partial groups.
template <int N, int M>
__device__ __forceinline__ void edge_group(
    const float* __restrict__ src,
    const float* __restrict__ h, const float* __restrict__ g,
    float* __restrict__ adst, float* __restrict__ ddst, int j)
{
#pragma unroll 4
    for (int r = 0; r < 4; ++r) {
        const int pos = 4 * j + r;
        if (pos >= M) break;
        const int s0 = 2 * pos + 1;
        float a = 0.f, d = 0.f;
#pragma unroll
        for (int q = 0; q < 8; ++q) {
            const float v = refl_load(src, s0 - q, N);
            a = fmaf(h[q], v, a);
            d = fmaf(g[q], v, d);
        }
        ddst[pos] = d;
        adst[pos] = a;
    }
}

// One DWT level, NITER windows loaded upfront (R10-proven form).
template <int N, int M, int NITER>
__device__ __forceinline__ void dwt_level(
    const float* __restrict__ src,
    const float* __restrict__ h, const float* __restrict__ g,
    float* __restrict__ adst, float* __restrict__ ddst, int tid)
{
    constexpr int ngroups = (M + 3) >> 2;
    constexpr int jmax = (N - 10) >> 3;
    constexpr int rem = ngroups - NITER * 256;       // leftover (edge) groups
    constexpr bool full = (NITER * 256 <= ngroups);  // all t-slots valid

    float w[NITER][16];
#pragma unroll
    for (int t = 0; t < NITER; ++t) {
        const int j = tid + t * 256;
        if (full || j < ngroups)
            load_window<N>(src, j, &w[t][0]);
    }
    __builtin_amdgcn_sched_barrier(0);   // pin: loads issued before compute

#pragma unroll
    for (int t = 0; t < NITER; ++t) {
        const int j = tid + t * 256;
        if (!full && j >= ngroups) break;
        const int p0 = 4 * j;
        if (j >= 1 && j <= jmax && p0 + 3 < M) {
            float aa[4], dd[4];
#pragma unroll
            for (int r = 0; r < 4; ++r) {
                float a = 0.f, d = 0.f;
#pragma unroll
                for (int q = 0; q < 8; ++q) {
                    const float v = w[t][2 * r + 7 - q];   // src[2(p0+r)+1-q]
                    a = fmaf(h[q], v, a);
                    d = fmaf(g[q], v, d);
                }
                aa[r] = a; dd[r] = d;
            }
#pragma unroll
            for (int r = 0; r < 4; ++r) ddst[p0 + r] = dd[r];
#pragma unroll
            for (int r = 0; r < 4; ++r) adst[p0 + r] = aa[r];
        } else {
            edge_group<N, M>(src, h, g, adst, ddst, j);
        }
    }
    if constexpr (rem > 0) {
        if (tid < rem)
            edge_group<N, M>(src, h, g, adst, ddst, NITER * 256 + tid);
    }
}

// ---- R16: a1-only LDS, a2 via global scratch, 8 blocks/CU ----
__global__ __launch_bounds__(256, 8)
void wavedec5_hiocc(const float* __restrict__ x,
                    const float* __restrict__ dlo,
                    const float* __restrict__ dhi,
                    float* __restrict__ out,
                    float* __restrict__ ws)
{
    __shared__ __align__(16) float bufA[4100];  // a1; later a3 @0, a4 @2048

    const int row = blockIdx.x;
    const int tid = threadIdx.x;

    float h[8], g[8];
#pragma unroll
    for (int i = 0; i < 8; ++i) { h[i] = dlo[i]; g[i] = dhi[i]; }

    const float* __restrict__ xr = x + (size_t)row * N0;
    float* __restrict__ a2g = ws + (size_t)row * WS_STRIDE;   // 2053 fl, L2-local
    float* __restrict__ a3p = bufA;                           // 1030 fl
    float* __restrict__ a4p = bufA + 2048;                    // 518 fl

    // L1: global x -> bufA(a1), d1 -> global
    dwt_level<N0, L1n, 4>(xr, h, g, bufA,
                          out + OFF_D1 + (size_t)row * L1n, tid);
    barrier_lds();
    // L2: bufA(a1) -> a2g (global scratch), d2 -> global
    dwt_level<L1n, L2n, 2>(bufA, h, g, a2g,
                           out + OFF_D2 + (size_t)row * L2n, tid);
    __syncthreads();   // full drain: a2g stores must be visible to block
    // L3: a2g -> bufA(a3, a1 dead), d3 -> global
    dwt_level<L2n, L3n, 1>(a2g, h, g, a3p,
                           out + OFF_D3 + (size_t)row * L3n, tid);
    barrier_lds();
    // L4: bufA(a3) -> bufA+2048(a4), d4 -> global (disjoint LDS ranges)
    dwt_level<L3n, L4n, 1>(a3p, h, g, a4p,
                           out + OFF_D4 + (size_t)row * L4n, tid);
    barrier_lds();
    // L5: a4 -> approx & d5 straight to global
    dwt_level<L4n, L5n, 1>(a4p, h, g,
                           out + (size_t)row * L5n,
                           out + OFF_D5 + (size_t)row * L5n, tid);
}

// ---- fallback: R10 full-LDS kernel (proven 58.4 us) ----
__global__ __launch_bounds__(256, 4)
void wavedec5_lds(const float* __restrict__ x,
                  const float* __restrict__ dlo,
                  const float* __restrict__ dhi,
                  float* __restrict__ out)
{
    __shared__ __align__(16) float bufA[4100];  // a1 / a3
    __shared__ __align__(16) float bufB[2056];  // a2 / a4

    const int row = blockIdx.x;
    const int tid = threadIdx.x;

    float h[8], g[8];
#pragma unroll
    for (int i = 0; i < 8; ++i) { h[i] = dlo[i]; g[i] = dhi[i]; }

    const float* __restrict__ xr = x + (size_t)row * N0;

    dwt_level<N0, L1n, 4>(xr, h, g, bufA,
                          out + OFF_D1 + (size_t)row * L1n, tid);
    barrier_lds();
    dwt_level<L1n, L2n, 2>(bufA, h, g, bufB,
                           out + OFF_D2 + (size_t)row * L2n, tid);
    barrier_lds();
    dwt_level<L2n, L3n, 1>(bufB, h, g, bufA,
                           out + OFF_D3 + (size_t)row * L3n, tid);
    barrier_lds();
    dwt_level<L3n, L4n, 1>(bufA, h, g, bufB,
                           out + OFF_D4 + (size_t)row * L4n, tid);
    barrier_lds();
    dwt_level<L4n, L5n, 1>(bufB, h, g,
                           out + (size_t)row * L5n,
                           out + OFF_D5 + (size_t)row * L5n, tid);
}

extern "C" void kernel_launch(void* const* d_in, const int* in_sizes, int n_in,
                              void* d_out, int out_size, void* d_ws, size_t ws_size,
                              hipStream_t stream) {
    const float* x   = (const float*)d_in[0];
    const float* dlo = (const float*)d_in[1];
    const float* dhi = (const float*)d_in[2];
    float* out = (float*)d_out;
    if (ws_size >= WS_NEED && d_ws != nullptr) {
        wavedec5_hiocc<<<ROWS, 256, 0, stream>>>(x, dlo, dhi, out, (float*)d_ws);
    } else {
        wavedec5_lds<<<ROWS, 256, 0, stream>>>(x, dlo, dhi, out);
    }
}

// Round 17
// 59.964 us; speedup vs baseline: 1.7810x; 1.7810x over previous
//
#include <hip/hip_runtime.h>

// 5-level wavedec (filter len 8, pywt 'symmetric'), 4096 rows of 8192 f32.
// Lengths: 8192 -> 4099 -> 2053 -> 1030 -> 518 -> 262
// Out: approx(262) @0, d5(262), d4(518), d3(1030), d2(2053), d1(4099).
//
// R17 = R10/R14 (best, 58.4us) + asm register pins on each loaded window.
// R9/R10/R12/R13 all failed to materialize load batching (VGPR stuck at
// 40-44): IR-level sinking moves loads back into compute, and
// sched_barrier can't stop it (backend-only). An empty inline asm with
// "+v" operands creates a DATA dependency: all 16 floats of a window must
// be in registers at the pin. Pins are interleaved with per-window compute
// so batch t+1..3's latency hides under batch t's 128 FMAs.

static constexpr int ROWS = 4096;
static constexpr int N0 = 8192;
static constexpr int L1n = 4099, L2n = 2053, L3n = 1030, L4n = 518, L5n = 262;
static constexpr size_t OFF_D5 = 1073152u;
static constexpr size_t OFF_D4 = 2146304u;
static constexpr size_t OFF_D3 = 4268032u;
static constexpr size_t OFF_D2 = 8486912u;
static constexpr size_t OFF_D1 = 16896000u;

#define PIN16(W) asm volatile("" : \
    "+v"((W)[0]),  "+v"((W)[1]),  "+v"((W)[2]),  "+v"((W)[3]), \
    "+v"((W)[4]),  "+v"((W)[5]),  "+v"((W)[6]),  "+v"((W)[7]), \
    "+v"((W)[8]),  "+v"((W)[9]),  "+v"((W)[10]), "+v"((W)[11]), \
    "+v"((W)[12]), "+v"((W)[13]), "+v"((W)[14]), "+v"((W)[15]))

// Barrier ordering LDS only (no vmcnt drain of global d-stores).
__device__ __forceinline__ void barrier_lds() {
    asm volatile("s_waitcnt lgkmcnt(0)\n\ts_barrier" ::: "memory");
}

__device__ __forceinline__ float refl_load(const float* __restrict__ s, int idx, int n) {
    int i = (idx < 0) ? (-1 - idx) : ((idx >= n) ? (2 * n - 1 - idx) : idx);
    return s[i];
}

// Clamped 16-float window load for group j: w[t] = src[8j-6+t]
template <int N>
__device__ __forceinline__ void load_window(const float* __restrict__ src,
                                            int j, float* __restrict__ w) {
    constexpr int jmax = (N - 10) >> 3;
    const int jb = j < 1 ? 1 : (j > jmax ? jmax : j);
    const float2* __restrict__ s2 = reinterpret_cast<const float2*>(src) + (4 * jb - 3);
#pragma unroll
    for (int t = 0; t < 8; ++t) {
        const float2 v = s2[t];
        w[2 * t] = v.x; w[2 * t + 1] = v.y;
    }
}

// Branchy symmetric-reflect path for edge / partial groups.
template <int N, int M>
__device__ __forceinline__ void edge_group(
    const float* __restrict__ src,
    const float* __restrict__ h, const float* __restrict__ g,
    float* __restrict__ adst, float* __restrict__ ddst, int j)
{
#pragma unroll 4
    for (int r = 0; r < 4; ++r) {
        const int pos = 4 * j + r;
        if (pos >= M) break;
        const int s0 = 2 * pos + 1;
        float a = 0.f, d = 0.f;
#pragma unroll
        for (int q = 0; q < 8; ++q) {
            const float v = refl_load(src, s0 - q, N);
            a = fmaf(h[q], v, a);
            d = fmaf(g[q], v, d);
        }
        ddst[pos] = d;
        adst[pos] = a;
    }
}

// One DWT level: NITER windows loaded upfront, pinned live via asm,
// compute interleaved per window (pipeline depth NITER).
template <int N, int M, int NITER>
__device__ __forceinline__ void dwt_level(
    const float* __restrict__ src,
    const float* __restrict__ h, const float* __restrict__ g,
    float* __restrict__ adst, float* __restrict__ ddst, int tid)
{
    constexpr int ngroups = (M + 3) >> 2;
    constexpr int jmax = (N - 10) >> 3;
    constexpr int rem = ngroups - NITER * 256;       // leftover (edge) groups
    constexpr bool full = (NITER * 256 <= ngroups);  // all t-slots valid

    float w[NITER][16];
#pragma unroll
    for (int t = 0; t < NITER; ++t)
        load_window<N>(src, tid + t * 256, &w[t][0]);   // clamped, unconditional
    __builtin_amdgcn_sched_barrier(0);

#pragma unroll
    for (int t = 0; t < NITER; ++t) {
        PIN16(w[t]);   // data dep: window t fully resident HERE
        const int j = tid + t * 256;
        if (!full && j >= ngroups) break;
        const int p0 = 4 * j;
        if (j >= 1 && j <= jmax && p0 + 3 < M) {
            float aa[4], dd[4];
#pragma unroll
            for (int r = 0; r < 4; ++r) {
                float a = 0.f, d = 0.f;
#pragma unroll
                for (int q = 0; q < 8; ++q) {
                    const float v = w[t][2 * r + 7 - q];   // src[2(p0+r)+1-q]
                    a = fmaf(h[q], v, a);
                    d = fmaf(g[q], v, d);
                }
                aa[r] = a; dd[r] = d;
            }
#pragma unroll
            for (int r = 0; r < 4; ++r) ddst[p0 + r] = dd[r];
#pragma unroll
            for (int r = 0; r < 4; ++r) adst[p0 + r] = aa[r];
        } else {
            edge_group<N, M>(src, h, g, adst, ddst, j);
        }
    }
    if constexpr (rem > 0) {
        if (tid < rem)
            edge_group<N, M>(src, h, g, adst, ddst, NITER * 256 + tid);
    }
}

__global__ __launch_bounds__(256, 4)
void wavedec5_kernel(const float* __restrict__ x,
                     const float* __restrict__ dlo,
                     const float* __restrict__ dhi,
                     float* __restrict__ out)
{
    __shared__ __align__(16) float bufA[4100];  // a1 / a3
    __shared__ __align__(16) float bufB[2056];  // a2 / a4

    const int row = blockIdx.x;
    const int tid = threadIdx.x;

    float h[8], g[8];
#pragma unroll
    for (int i = 0; i < 8; ++i) { h[i] = dlo[i]; g[i] = dhi[i]; }

    const float* __restrict__ xr = x + (size_t)row * N0;

    // L1: global -> bufA, d1 -> global (4-deep pinned pipeline)
    dwt_level<N0, L1n, 4>(xr, h, g, bufA,
                          out + OFF_D1 + (size_t)row * L1n, tid);
    barrier_lds();
    // L2: bufA -> bufB, d2 -> global (2-deep)
    dwt_level<L1n, L2n, 2>(bufA, h, g, bufB,
                           out + OFF_D2 + (size_t)row * L2n, tid);
    barrier_lds();
    // L3: bufB -> bufA, d3 -> global
    dwt_level<L2n, L3n, 1>(bufB, h, g, bufA,
                           out + OFF_D3 + (size_t)row * L3n, tid);
    barrier_lds();
    // L4: bufA -> bufB, d4 -> global
    dwt_level<L3n, L4n, 1>(bufA, h, g, bufB,
                           out + OFF_D4 + (size_t)row * L4n, tid);
    barrier_lds();
    // L5: bufB -> approx & d5 straight to global
    dwt_level<L4n, L5n, 1>(bufB, h, g,
                           out + (size_t)row * L5n,
                           out + OFF_D5 + (size_t)row * L5n, tid);
}

extern "C" void kernel_launch(void* const* d_in, const int* in_sizes, int n_in,
                              void* d_out, int out_size, void* d_ws, size_t ws_size,
                              hipStream_t stream) {
    const float* x   = (const float*)d_in[0];
    const float* dlo = (const float*)d_in[1];
    const float* dhi = (const float*)d_in[2];
    float* out = (float*)d_out;
    wavedec5_kernel<<<ROWS, 256, 0, stream>>>(x, dlo, dhi, out);
}